// Round 2
// baseline (578.606 us; speedup 1.0000x reference)
//
#include <hip/hip_runtime.h>
#include <hip/hip_bf16.h>

// ---------------- utility ----------------

__global__ void zero_two_kernel(int* __restrict__ a, int* __restrict__ b, int n) {
    int i = blockIdx.x * blockDim.x + threadIdx.x;
    if (i < n) { a[i] = 0; b[i] = 0; }
}

// ---------------- CSR build ----------------
// edge_index arrives as int32 (harness contract: integer -> const int*),
// flat [2, E]: src = ei[e], dst = ei[E + e].

__global__ void count_deg_kernel(const int* __restrict__ ei, int E, int N, int* __restrict__ deg) {
    int e = blockIdx.x * blockDim.x + threadIdx.x;
    int stride = gridDim.x * blockDim.x;
    for (; e < E; e += stride) {
        int d = ei[E + e];               // dst
        if ((unsigned)d < (unsigned)N) atomicAdd(&deg[d], 1);
    }
}

__global__ void compute_dinv_kernel(const int* __restrict__ deg, float* __restrict__ dinv, int N) {
    int i = blockIdx.x * blockDim.x + threadIdx.x;
    if (i < N) {
        // self-loop adds 1 to in-degree; deg always >= 1
        dinv[i] = rsqrtf((float)(deg[i] + 1));
    }
}

#define SCAN_T 1024

__global__ void scan_block_sum_kernel(const int* __restrict__ deg, int N, int* __restrict__ bsum) {
    __shared__ int sm[SCAN_T];
    int t = threadIdx.x;
    int gi = blockIdx.x * SCAN_T + t;
    sm[t] = (gi < N) ? deg[gi] : 0;
    __syncthreads();
    for (int off = SCAN_T / 2; off > 0; off >>= 1) {
        if (t < off) sm[t] += sm[t + off];
        __syncthreads();
    }
    if (t == 0) bsum[blockIdx.x] = sm[0];
}

__global__ void scan_exclusive_sums_kernel(int* __restrict__ bsum, int nb) {
    if (blockIdx.x == 0 && threadIdx.x == 0) {
        int run = 0;
        for (int b = 0; b < nb; ++b) {
            int v = bsum[b];
            bsum[b] = run;
            run += v;
        }
    }
}

__global__ void scan_write_kernel(const int* __restrict__ deg, int N,
                                  const int* __restrict__ bsum, int* __restrict__ rowptr) {
    __shared__ int sm[2][SCAN_T];
    int t = threadIdx.x;
    int gi = blockIdx.x * SCAN_T + t;
    int val = (gi < N) ? deg[gi] : 0;
    sm[0][t] = val;
    int pin = 0;
    for (int off = 1; off < SCAN_T; off <<= 1) {
        __syncthreads();
        int v = sm[pin][t];
        if (t >= off) v += sm[pin][t - off];
        sm[pin ^ 1][t] = v;
        pin ^= 1;
    }
    __syncthreads();
    int incl = sm[pin][t];
    int excl = incl - val;
    int base = bsum[blockIdx.x];
    if (gi < N) rowptr[gi] = base + excl;
    if (gi == N - 1) rowptr[N] = base + incl;   // == E (valid edges)
}

__global__ void fill_csr_kernel(const int* __restrict__ ei, int E, int N,
                                const int* __restrict__ rowptr, int* __restrict__ cursor,
                                int* __restrict__ col, float* __restrict__ wgt,
                                const float* __restrict__ dinv) {
    int e = blockIdx.x * blockDim.x + threadIdx.x;
    int stride = gridDim.x * blockDim.x;
    for (; e < E; e += stride) {
        int s = ei[e];
        int d = ei[E + e];
        if ((unsigned)s >= (unsigned)N || (unsigned)d >= (unsigned)N) continue;
        int pos = atomicAdd(&cursor[d], 1);
        int idx = rowptr[d] + pos;
        col[idx] = s;
        wgt[idx] = dinv[s];
    }
}

// ---------------- GEMM: H[N,128] = X[N,128] @ W[128,128] ----------------
// Block: 256 threads, 64 rows per block, each thread 4 rows x 8 cols.

__global__ __launch_bounds__(256) void gemm_nt128_kernel(const float* __restrict__ X,
                                                         const float* __restrict__ W,
                                                         float* __restrict__ H, int N) {
    __shared__ float Wl[32][128];   // [k][j]
    __shared__ float Xl[32][68];    // transposed [k][row], padded
    int tid = threadIdx.x;
    int tx = tid & 15;              // col group: cols tx*8 .. tx*8+7
    int ty = tid >> 4;              // row group: rows ty*4 .. ty*4+3
    int rowBase = blockIdx.x * 64;

    float acc[4][8];
#pragma unroll
    for (int i = 0; i < 4; ++i)
#pragma unroll
        for (int j = 0; j < 8; ++j) acc[i][j] = 0.f;

    for (int k0 = 0; k0 < 128; k0 += 32) {
        for (int i = tid; i < 32 * 128; i += 256) {
            int kk = i >> 7, j = i & 127;
            Wl[kk][j] = W[(size_t)(k0 + kk) * 128 + j];
        }
        for (int i = tid; i < 64 * 32; i += 256) {
            int r = i >> 5, kk = i & 31;
            int row = rowBase + r;
            Xl[kk][r] = (row < N) ? X[(size_t)row * 128 + k0 + kk] : 0.f;
        }
        __syncthreads();
#pragma unroll
        for (int kk = 0; kk < 32; ++kk) {
            float4 xv = *(const float4*)&Xl[kk][ty * 4];
            float4 wa = *(const float4*)&Wl[kk][tx * 8];
            float4 wb = *(const float4*)&Wl[kk][tx * 8 + 4];
            float xs[4] = {xv.x, xv.y, xv.z, xv.w};
            float ws[8] = {wa.x, wa.y, wa.z, wa.w, wb.x, wb.y, wb.z, wb.w};
#pragma unroll
            for (int i = 0; i < 4; ++i)
#pragma unroll
                for (int j = 0; j < 8; ++j) acc[i][j] += xs[i] * ws[j];
        }
        __syncthreads();
    }

#pragma unroll
    for (int i = 0; i < 4; ++i) {
        int row = rowBase + ty * 4 + i;
        if (row < N) {
            float* dst = &H[(size_t)row * 128 + tx * 8];
            *(float4*)dst = make_float4(acc[i][0], acc[i][1], acc[i][2], acc[i][3]);
            *(float4*)(dst + 4) = make_float4(acc[i][4], acc[i][5], acc[i][6], acc[i][7]);
        }
    }
}

// ---------------- GEMM: H[N,16] = X[N,128] @ W[128,16] ----------------
// Block: 256 threads, 64 rows per block, 4 threads per row (4 cols each).

__global__ __launch_bounds__(256) void gemm_nt16_kernel(const float* __restrict__ X,
                                                        const float* __restrict__ W,
                                                        float* __restrict__ H, int N) {
    __shared__ float Wl[128][16];
    __shared__ float Xl[64][132];   // padded
    int tid = threadIdx.x;
    int r = tid >> 2;    // 0..63
    int cg = tid & 3;    // 0..3 -> cols cg*4 .. cg*4+3
    int rowBase = blockIdx.x * 64;

    for (int i = tid; i < 128 * 16; i += 256) Wl[i >> 4][i & 15] = W[i];
    for (int i = tid; i < 64 * 128; i += 256) {
        int rr = i >> 7, kk = i & 127;
        int row = rowBase + rr;
        Xl[rr][kk] = (row < N) ? X[(size_t)row * 128 + kk] : 0.f;
    }
    __syncthreads();

    float a0 = 0.f, a1 = 0.f, a2 = 0.f, a3 = 0.f;
#pragma unroll
    for (int k = 0; k < 128; ++k) {
        float xv = Xl[r][k];
        float4 w = *(const float4*)&Wl[k][cg * 4];
        a0 += xv * w.x;
        a1 += xv * w.y;
        a2 += xv * w.z;
        a3 += xv * w.w;
    }
    int row = rowBase + r;
    if (row < N) {
        *(float4*)&H[(size_t)row * 16 + cg * 4] = make_float4(a0, a1, a2, a3);
    }
}

// ---------------- Aggregation F=128 (layer 1), fused bias+relu ----------------
// One block (128 threads) per node; thread t owns feature t.

__global__ __launch_bounds__(128) void agg128_kernel(const float* __restrict__ H,
                                                     const int* __restrict__ rowptr,
                                                     const int* __restrict__ col,
                                                     const float* __restrict__ wgt,
                                                     const float* __restrict__ dinv,
                                                     const float* __restrict__ bias,
                                                     float* __restrict__ out, int N) {
    int i = blockIdx.x;
    int t = threadIdx.x;
    int r0 = rowptr[i], r1 = rowptr[i + 1];
    float di = dinv[i];
    // inner = sum_s dinv[s]*h[s] + dinv[i]*h[i]  (self-loop)
    float acc = di * H[(size_t)i * 128 + t];
    for (int e = r0; e < r1; ++e) {
        int s = col[e];
        float w = wgt[e];
        acc += w * H[(size_t)s * 128 + t];
    }
    float v = di * acc + bias[t];
    out[(size_t)i * 128 + t] = fmaxf(v, 0.f);
}

// ---------------- Aggregation F=16 (layer 2), fused bias ----------------
// 256 threads = 16 groups of 16 lanes; one group per node.

__global__ __launch_bounds__(256) void agg16_kernel(const float* __restrict__ H,
                                                    const int* __restrict__ rowptr,
                                                    const int* __restrict__ col,
                                                    const float* __restrict__ wgt,
                                                    const float* __restrict__ dinv,
                                                    const float* __restrict__ bias,
                                                    float* __restrict__ out, int N) {
    int g = threadIdx.x >> 4;
    int t = threadIdx.x & 15;
    int i = blockIdx.x * 16 + g;
    if (i >= N) return;
    int r0 = rowptr[i], r1 = rowptr[i + 1];
    float di = dinv[i];
    float acc = di * H[(size_t)i * 16 + t];
    for (int e = r0; e < r1; ++e) {
        int s = col[e];
        float w = wgt[e];
        acc += w * H[(size_t)s * 16 + t];
    }
    out[(size_t)i * 16 + t] = di * acc + bias[t];
}

// ---------------- Launch ----------------

extern "C" void kernel_launch(void* const* d_in, const int* in_sizes, int n_in,
                              void* d_out, int out_size, void* d_ws, size_t ws_size,
                              hipStream_t stream) {
    const float* x = (const float*)d_in[0];
    const int* ei = (const int*)d_in[1];      // int32 per harness contract
    const float* W1 = (const float*)d_in[2];
    const float* b1 = (const float*)d_in[3];
    const float* W2 = (const float*)d_in[4];
    const float* b2 = (const float*)d_in[5];
    float* out = (float*)d_out;

    const int N = in_sizes[0] / 128;   // 100000
    const int E = in_sizes[1] / 2;     // 1600000

    // workspace layout (256B aligned)
    char* base = (char*)d_ws;
    size_t off = 0;
    auto align_up = [](size_t v) { return (v + 255) & ~(size_t)255; };

    int* deg = (int*)(base + off);        off = align_up(off + (size_t)N * 4);
    int* rowptr = (int*)(base + off);     off = align_up(off + (size_t)(N + 1) * 4);
    int* cursor = (int*)(base + off);     off = align_up(off + (size_t)N * 4);
    float* dinv = (float*)(base + off);   off = align_up(off + (size_t)N * 4);
    int* colIdx = (int*)(base + off);     off = align_up(off + (size_t)E * 4);
    float* wgt = (float*)(base + off);    off = align_up(off + (size_t)E * 4);
    int* bsum = (int*)(base + off);       off = align_up(off + (size_t)256 * 4);
    float* h1 = (float*)(base + off);     off = align_up(off + (size_t)N * 128 * 4);
    float* g1 = (float*)(base + off);     off = align_up(off + (size_t)N * 128 * 4);
    float* h2 = h1;  // h1 dead after agg128; reuse for layer-2 transformed features

    zero_two_kernel<<<(N + 255) / 256, 256, 0, stream>>>(deg, cursor, N);

    count_deg_kernel<<<2048, 256, 0, stream>>>(ei, E, N, deg);
    compute_dinv_kernel<<<(N + 255) / 256, 256, 0, stream>>>(deg, dinv, N);

    int nb = (N + SCAN_T - 1) / SCAN_T;
    scan_block_sum_kernel<<<nb, SCAN_T, 0, stream>>>(deg, N, bsum);
    scan_exclusive_sums_kernel<<<1, 1, 0, stream>>>(bsum, nb);
    scan_write_kernel<<<nb, SCAN_T, 0, stream>>>(deg, N, bsum, rowptr);

    fill_csr_kernel<<<2048, 256, 0, stream>>>(ei, E, N, rowptr, cursor, colIdx, wgt, dinv);

    // layer 1: h1 = x @ W1 ; g1 = relu(Ahat * h1 + b1)
    gemm_nt128_kernel<<<(N + 63) / 64, 256, 0, stream>>>(x, W1, h1, N);
    agg128_kernel<<<N, 128, 0, stream>>>(h1, rowptr, colIdx, wgt, dinv, b1, g1, N);

    // layer 2: h2 = g1 @ W2 ; out = Ahat * h2 + b2
    gemm_nt16_kernel<<<(N + 63) / 64, 256, 0, stream>>>(g1, W2, h2, N);
    agg16_kernel<<<(N + 15) / 16, 256, 0, stream>>>(h2, rowptr, colIdx, wgt, dinv, b2, out, N);
}

// Round 3
// 423.994 us; speedup vs baseline: 1.3647x; 1.3647x over previous
//
#include <hip/hip_runtime.h>
#include <hip/hip_bf16.h>

// ---------------- helpers ----------------

__device__ __forceinline__ float bf2f(unsigned short u) {
    return __uint_as_float(((unsigned int)u) << 16);
}
__device__ __forceinline__ unsigned short f2bf(float f) {
    unsigned int u = __float_as_uint(f);
    unsigned int r = (u + 0x7fffu + ((u >> 16) & 1u)) >> 16;  // round-to-nearest-even
    return (unsigned short)r;
}

__global__ void zero_two_kernel(int* __restrict__ a, int* __restrict__ b, int n) {
    int i = blockIdx.x * blockDim.x + threadIdx.x;
    if (i < n) { a[i] = 0; b[i] = 0; }
}

// ---------------- CSR build ----------------
// edge_index is int32, flat [2, E]: src = ei[e], dst = ei[E + e].

__global__ void count_deg_kernel(const int* __restrict__ ei, int E, int N, int* __restrict__ deg) {
    int e = blockIdx.x * blockDim.x + threadIdx.x;
    int stride = gridDim.x * blockDim.x;
    for (; e < E; e += stride) {
        int d = ei[E + e];
        if ((unsigned)d < (unsigned)N) atomicAdd(&deg[d], 1);
    }
}

__global__ void compute_dinv_kernel(const int* __restrict__ deg, float* __restrict__ dinv, int N) {
    int i = blockIdx.x * blockDim.x + threadIdx.x;
    if (i < N) dinv[i] = rsqrtf((float)(deg[i] + 1));   // +1 self-loop
}

#define SCAN_T 1024

__global__ void scan_block_sum_kernel(const int* __restrict__ deg, int N, int* __restrict__ bsum) {
    __shared__ int sm[SCAN_T];
    int t = threadIdx.x;
    int gi = blockIdx.x * SCAN_T + t;
    sm[t] = (gi < N) ? deg[gi] : 0;
    __syncthreads();
    for (int off = SCAN_T / 2; off > 0; off >>= 1) {
        if (t < off) sm[t] += sm[t + off];
        __syncthreads();
    }
    if (t == 0) bsum[blockIdx.x] = sm[0];
}

__global__ void scan_exclusive_sums_kernel(int* __restrict__ bsum, int nb) {
    if (blockIdx.x == 0 && threadIdx.x == 0) {
        int run = 0;
        for (int b = 0; b < nb; ++b) { int v = bsum[b]; bsum[b] = run; run += v; }
    }
}

__global__ void scan_write_kernel(const int* __restrict__ deg, int N,
                                  const int* __restrict__ bsum, int* __restrict__ rowptr) {
    __shared__ int sm[2][SCAN_T];
    int t = threadIdx.x;
    int gi = blockIdx.x * SCAN_T + t;
    int val = (gi < N) ? deg[gi] : 0;
    sm[0][t] = val;
    int pin = 0;
    for (int off = 1; off < SCAN_T; off <<= 1) {
        __syncthreads();
        int v = sm[pin][t];
        if (t >= off) v += sm[pin][t - off];
        sm[pin ^ 1][t] = v;
        pin ^= 1;
    }
    __syncthreads();
    int incl = sm[pin][t];
    int excl = incl - val;
    int base = bsum[blockIdx.x];
    if (gi < N) rowptr[gi] = base + excl;
    if (gi == N - 1) rowptr[N] = base + incl;
}

// packed per-edge record: .x = src node, .y = float bits of dinv[src]
__global__ void fill_csr_kernel(const int* __restrict__ ei, int E, int N,
                                const int* __restrict__ rowptr, int* __restrict__ cursor,
                                int2* __restrict__ colwgt, const float* __restrict__ dinv) {
    int e = blockIdx.x * blockDim.x + threadIdx.x;
    int stride = gridDim.x * blockDim.x;
    for (; e < E; e += stride) {
        int s = ei[e];
        int d = ei[E + e];
        if ((unsigned)s >= (unsigned)N || (unsigned)d >= (unsigned)N) continue;
        int pos = atomicAdd(&cursor[d], 1);
        colwgt[rowptr[d] + pos] = make_int2(s, __float_as_int(dinv[s]));
    }
}

// ---------------- GEMM: H[N,128](bf16) = X[N,128] @ W[128,128] ----------------

__global__ __launch_bounds__(256) void gemm_nt128_kernel(const float* __restrict__ X,
                                                         const float* __restrict__ W,
                                                         unsigned short* __restrict__ H, int N) {
    __shared__ float Wl[32][128];
    __shared__ float Xl[32][68];
    int tid = threadIdx.x;
    int tx = tid & 15;              // cols tx*8 .. tx*8+7
    int ty = tid >> 4;              // rows ty*4 .. ty*4+3
    int rowBase = blockIdx.x * 64;

    float acc[4][8];
#pragma unroll
    for (int i = 0; i < 4; ++i)
#pragma unroll
        for (int j = 0; j < 8; ++j) acc[i][j] = 0.f;

    for (int k0 = 0; k0 < 128; k0 += 32) {
        for (int i = tid; i < 32 * 128; i += 256) {
            int kk = i >> 7, j = i & 127;
            Wl[kk][j] = W[(size_t)(k0 + kk) * 128 + j];
        }
        for (int i = tid; i < 64 * 32; i += 256) {
            int r = i >> 5, kk = i & 31;
            int row = rowBase + r;
            Xl[kk][r] = (row < N) ? X[(size_t)row * 128 + k0 + kk] : 0.f;
        }
        __syncthreads();
#pragma unroll
        for (int kk = 0; kk < 32; ++kk) {
            float4 xv = *(const float4*)&Xl[kk][ty * 4];
            float4 wa = *(const float4*)&Wl[kk][tx * 8];
            float4 wb = *(const float4*)&Wl[kk][tx * 8 + 4];
            float xs[4] = {xv.x, xv.y, xv.z, xv.w};
            float ws[8] = {wa.x, wa.y, wa.z, wa.w, wb.x, wb.y, wb.z, wb.w};
#pragma unroll
            for (int i = 0; i < 4; ++i)
#pragma unroll
                for (int j = 0; j < 8; ++j) acc[i][j] += xs[i] * ws[j];
        }
        __syncthreads();
    }

#pragma unroll
    for (int i = 0; i < 4; ++i) {
        int row = rowBase + ty * 4 + i;
        if (row < N) {
            ushort us[8];
#pragma unroll
            for (int j = 0; j < 8; ++j) us[j] = f2bf(acc[i][j]);
            *(uint4*)&H[(size_t)row * 128 + tx * 8] = *(const uint4*)us;  // 16B store
        }
    }
}

// ---------------- GEMM: H[N,16](bf16) = X[N,128] @ W[128,16] ----------------

__global__ __launch_bounds__(256) void gemm_nt16_kernel(const float* __restrict__ X,
                                                        const float* __restrict__ W,
                                                        unsigned short* __restrict__ H, int N) {
    __shared__ float Wl[128][16];
    __shared__ float Xl[64][132];
    int tid = threadIdx.x;
    int r = tid >> 2;
    int cg = tid & 3;
    int rowBase = blockIdx.x * 64;

    for (int i = tid; i < 128 * 16; i += 256) Wl[i >> 4][i & 15] = W[i];
    for (int i = tid; i < 64 * 128; i += 256) {
        int rr = i >> 7, kk = i & 127;
        int row = rowBase + rr;
        Xl[rr][kk] = (row < N) ? X[(size_t)row * 128 + kk] : 0.f;
    }
    __syncthreads();

    float a[4] = {0.f, 0.f, 0.f, 0.f};
#pragma unroll
    for (int k = 0; k < 128; ++k) {
        float xv = Xl[r][k];
        float4 w = *(const float4*)&Wl[k][cg * 4];
        a[0] += xv * w.x; a[1] += xv * w.y; a[2] += xv * w.z; a[3] += xv * w.w;
    }
    int row = rowBase + r;
    if (row < N) {
        ushort us[4];
#pragma unroll
        for (int j = 0; j < 4; ++j) us[j] = f2bf(a[j]);
        *(uint2*)&H[(size_t)row * 16 + cg * 4] = *(const uint2*)us;  // 8B store
    }
}

// ---------------- Aggregation F=128 (layer 1), bf16 table, fused bias+relu ----
// One wave per node; lane owns features 2l, 2l+1 (ushort2 = 4B/lane).

__global__ __launch_bounds__(128) void agg128_kernel(const unsigned short* __restrict__ H,
                                                     const int* __restrict__ rowptr,
                                                     const int2* __restrict__ colwgt,
                                                     const float* __restrict__ dinv,
                                                     const float* __restrict__ bias,
                                                     float* __restrict__ out, int N) {
    int lane = threadIdx.x & 63;
    int i = blockIdx.x * 2 + (threadIdx.x >> 6);
    if (i >= N) return;
    int r0 = rowptr[i], r1 = rowptr[i + 1];
    float di = dinv[i];

    ushort2 hv = *(const ushort2*)&H[(size_t)i * 128 + 2 * lane];
    float ax = di * bf2f(hv.x);
    float ay = di * bf2f(hv.y);

#pragma unroll 2
    for (int e = r0; e < r1; ++e) {
        int2 cw = colwgt[e];
        float w = __int_as_float(cw.y);
        ushort2 h2 = *(const ushort2*)&H[(size_t)cw.x * 128 + 2 * lane];
        ax += w * bf2f(h2.x);
        ay += w * bf2f(h2.y);
    }
    float2 b = *(const float2*)&bias[2 * lane];
    float2 o;
    o.x = fmaxf(di * ax + b.x, 0.f);
    o.y = fmaxf(di * ay + b.y, 0.f);
    *(float2*)&out[(size_t)i * 128 + 2 * lane] = o;
}

// ---------------- Aggregation F=16 (layer 2), bf16 table, fused bias ----------
// 16 lanes per node; lane owns 1 feature. 256-thr block = 16 nodes.

__global__ __launch_bounds__(256) void agg16_kernel(const unsigned short* __restrict__ H,
                                                    const int* __restrict__ rowptr,
                                                    const int2* __restrict__ colwgt,
                                                    const float* __restrict__ dinv,
                                                    const float* __restrict__ bias,
                                                    float* __restrict__ out, int N) {
    int t = threadIdx.x & 15;
    int i = blockIdx.x * 16 + (threadIdx.x >> 4);
    if (i >= N) return;
    int r0 = rowptr[i], r1 = rowptr[i + 1];
    float di = dinv[i];

    float acc = di * bf2f(H[(size_t)i * 16 + t]);
#pragma unroll 2
    for (int e = r0; e < r1; ++e) {
        int2 cw = colwgt[e];
        acc += __int_as_float(cw.y) * bf2f(H[(size_t)cw.x * 16 + t]);
    }
    out[(size_t)i * 16 + t] = di * acc + bias[t];
}

// ---------------- Launch ----------------

extern "C" void kernel_launch(void* const* d_in, const int* in_sizes, int n_in,
                              void* d_out, int out_size, void* d_ws, size_t ws_size,
                              hipStream_t stream) {
    const float* x = (const float*)d_in[0];
    const int* ei = (const int*)d_in[1];
    const float* W1 = (const float*)d_in[2];
    const float* b1 = (const float*)d_in[3];
    const float* W2 = (const float*)d_in[4];
    const float* b2 = (const float*)d_in[5];
    float* out = (float*)d_out;

    const int N = in_sizes[0] / 128;   // 100000
    const int E = in_sizes[1] / 2;     // 1600000

    char* base = (char*)d_ws;
    size_t off = 0;
    auto align_up = [](size_t v) { return (v + 255) & ~(size_t)255; };

    int* deg = (int*)(base + off);              off = align_up(off + (size_t)N * 4);
    int* rowptr = (int*)(base + off);           off = align_up(off + (size_t)(N + 1) * 4);
    int* cursor = (int*)(base + off);           off = align_up(off + (size_t)N * 4);
    float* dinv = (float*)(base + off);         off = align_up(off + (size_t)N * 4);
    int2* colwgt = (int2*)(base + off);         off = align_up(off + (size_t)E * 8);
    int* bsum = (int*)(base + off);             off = align_up(off + (size_t)256 * 4);
    unsigned short* h1 = (unsigned short*)(base + off);  off = align_up(off + (size_t)N * 128 * 2);
    float* g1 = (float*)(base + off);           off = align_up(off + (size_t)N * 128 * 4);
    unsigned short* h2 = (unsigned short*)(base + off);  off = align_up(off + (size_t)N * 16 * 2);

    zero_two_kernel<<<(N + 255) / 256, 256, 0, stream>>>(deg, cursor, N);

    count_deg_kernel<<<2048, 256, 0, stream>>>(ei, E, N, deg);
    compute_dinv_kernel<<<(N + 255) / 256, 256, 0, stream>>>(deg, dinv, N);

    int nb = (N + SCAN_T - 1) / SCAN_T;
    scan_block_sum_kernel<<<nb, SCAN_T, 0, stream>>>(deg, N, bsum);
    scan_exclusive_sums_kernel<<<1, 1, 0, stream>>>(bsum, nb);
    scan_write_kernel<<<nb, SCAN_T, 0, stream>>>(deg, N, bsum, rowptr);

    fill_csr_kernel<<<2048, 256, 0, stream>>>(ei, E, N, rowptr, cursor, colwgt, dinv);

    // layer 1: h1 = bf16(x @ W1) ; g1 = relu(Ahat * h1 + b1)   (g1 fp32)
    gemm_nt128_kernel<<<(N + 63) / 64, 256, 0, stream>>>(x, W1, h1, N);
    agg128_kernel<<<(N + 1) / 2, 128, 0, stream>>>(h1, rowptr, colwgt, dinv, b1, g1, N);

    // layer 2: h2 = bf16(g1 @ W2) ; out = Ahat * h2 + b2
    gemm_nt16_kernel<<<(N + 63) / 64, 256, 0, stream>>>(g1, W2, h2, N);
    agg16_kernel<<<(N + 15) / 16, 256, 0, stream>>>(h2, rowptr, colwgt, dinv, b2, out, N);
}